// Round 14
// baseline (549.747 us; speedup 1.0000x reference)
//
#include <hip/hip_runtime.h>
#include <hip/hip_bf16.h>
#include <hip/hip_cooperative_groups.h>
#include <math.h>

namespace cg = cooperative_groups;

// SS2D (VMamba) forward, MI355X. Constants from the reference.
#define DM 96
#define DI 192
#define NS 16
#define KK 4
#define RR 6
#define HH 56
#define WW 56
#define LL (HH*WW)       // 3136
#define RN (RR + 2*NS)   // 38
#define NCH 64
#define CLL (LL/NCH)     // 49

__device__ __forceinline__ float silu_f(float x) { return x / (1.f + __expf(-x)); }
__device__ __forceinline__ float softplus_f(float x) {
    return (x > 20.f) ? x : log1pf(__expf(x));
}

// ---- scan body (R13-proven): 8 lanes/chunk, 2 states/lane ----
template<int STP, bool TRANS>
__device__ __forceinline__ void scan_dir(
        const float* __restrict__ pd, const float* __restrict__ pu,
        const float* __restrict__ pB, const float* __restrict__ pC,
        float An0, float An1, float Dv, int c, int n,
        float* __restrict__ sP, float* __restrict__ sH,
        float* __restrict__ yo0, float* __restrict__ ysm, int im0) {
    float sd = 0.f, h0 = 0.f, h1 = 0.f;
#pragma unroll 7
    for (int tl = 0; tl < CLL; ++tl) {
        float dl = pd[STP * tl];
        float u  = pu[STP * tl];
        float B0 = pB[STP * NS * tl];
        float B1 = pB[STP * NS * tl + 8];
        float dA0 = __expf(dl * An0);
        float dA1 = __expf(dl * An1);
        float du = dl * u;
        h0 = fmaf(dA0, h0, du * B0);
        h1 = fmaf(dA1, h1, du * B1);
        sd += dl;
    }
    sP[c * NS + n]     = __expf(sd * An0);
    sP[c * NS + n + 8] = __expf(sd * An1);
    sH[c * NS + n]     = h0;
    sH[c * NS + n + 8] = h1;
    __syncthreads();
    float hin0 = 0.f, hin1 = 0.f;
    for (int cc = 0; cc < c; ++cc) {
        hin0 = fmaf(sP[cc * NS + n],     hin0, sH[cc * NS + n]);
        hin1 = fmaf(sP[cc * NS + n + 8], hin1, sH[cc * NS + n + 8]);
    }
    float h20 = hin0, h21 = hin1;
    float yreg[7];
#pragma unroll 7
    for (int tl = 0; tl < CLL; ++tl) {
        float dl = pd[STP * tl];
        float u  = pu[STP * tl];
        float B0 = pB[STP * NS * tl];
        float B1 = pB[STP * NS * tl + 8];
        float C0 = pC[STP * NS * tl];
        float C1 = pC[STP * NS * tl + 8];
        float dA0 = __expf(dl * An0);
        float dA1 = __expf(dl * An1);
        float du = dl * u;
        h20 = fmaf(dA0, h20, du * B0);
        h21 = fmaf(dA1, h21, du * B1);
        float acc = h20 * C0 + h21 * C1;
        acc += __shfl_xor(acc, 4, 64);
        acc += __shfl_xor(acc, 2, 64);
        acc += __shfl_xor(acc, 1, 64);
        acc = fmaf(Dv, u, acc);
        if ((tl & 7) == n) yreg[tl >> 3] = acc;
    }
    if (!TRANS) {
#pragma unroll
        for (int j = 0; j < 6; ++j)
            yo0[STP * (j * 8 + n)] = yreg[j];
        if (n == 0)
            yo0[STP * 48] = yreg[6];
    } else {
#pragma unroll
        for (int j = 0; j < 6; ++j) {
            int im = im0 + STP * (j * 8 + n);
            int w = im / HH, hh = im - w * HH;
            ysm[hh * 57 + w] = yreg[j];
        }
        if (n == 0) {
            int im = im0 + STP * 48;
            int w = im / HH, hh = im - w * HH;
            ysm[hh * 57 + w] = yreg[6];
        }
    }
}

// ================= Fused cooperative kernel: 768 blocks x 512 threads ========
__global__ __launch_bounds__(512, 6) void k_fused(
        const float* __restrict__ x, const float* __restrict__ ipw,
        const float* __restrict__ cw, const float* __restrict__ cb,
        const float* __restrict__ xpw, const float* __restrict__ dtw,
        const float* __restrict__ dtb, const float* __restrict__ alog,
        const float* __restrict__ Dsp, const float* __restrict__ lnw,
        const float* __restrict__ lnb, const float* __restrict__ ow,
        float* __restrict__ out,
        float* __restrict__ xc_t, float* __restrict__ z_nat,
        float* __restrict__ xconv, float* __restrict__ xs1,
        float* __restrict__ Bn, float* __restrict__ Cn,
        float* __restrict__ delta, float* __restrict__ y4) {
    cg::grid_group grid = cg::this_grid();
    __shared__ __align__(16) float sm[12608];       // 50,432 B union
    const int gid = blockIdx.x;
    const int tid = threadIdx.x;

    // ---------- Stage 1: in-proj GEMM (588 tiles of 64l x 32o) ----------
    if (gid < 588) {
        const int to = gid / 49, tl = gid % 49;
        const int l0 = tl * 64, o0 = to * 32;
        float* xt = sm;                 // 64*100
        float* wt = sm + 6400;          // 32*100
        for (int i = tid; i < 64 * 24; i += 512) {
            int r = i / 24, q = i % 24;
            *(float4*)&xt[r * 100 + 4 * q] = *(const float4*)&x[(size_t)(l0 + r) * DM + 4 * q];
        }
        for (int i = tid; i < 32 * 24; i += 512) {
            int r = i / 24, q = i % 24;
            *(float4*)&wt[r * 100 + 4 * q] = *(const float4*)&ipw[(size_t)(o0 + r) * DM + 4 * q];
        }
        __syncthreads();
        const int tx = tid & 15, ty = tid >> 4;     // ty 0..31
        float acc[2][2] = {};
        for (int c = 0; c < 96; c += 4) {
            float4 a0 = *(const float4*)&xt[ty * 100 + c];
            float4 a1 = *(const float4*)&xt[(ty + 32) * 100 + c];
            float4 b0 = *(const float4*)&wt[tx * 100 + c];
            float4 b1 = *(const float4*)&wt[(tx + 16) * 100 + c];
            acc[0][0] += a0.x * b0.x + a0.y * b0.y + a0.z * b0.z + a0.w * b0.w;
            acc[0][1] += a0.x * b1.x + a0.y * b1.y + a0.z * b1.z + a0.w * b1.w;
            acc[1][0] += a1.x * b0.x + a1.y * b0.y + a1.z * b0.z + a1.w * b0.w;
            acc[1][1] += a1.x * b1.x + a1.y * b1.y + a1.z * b1.z + a1.w * b1.w;
        }
        __syncthreads();
        float* ot = xt;                 // reuse as [o][l] 32x65
        ot[tx * 65 + ty]             = acc[0][0];
        ot[tx * 65 + ty + 32]        = acc[1][0];
        ot[(tx + 16) * 65 + ty]      = acc[0][1];
        ot[(tx + 16) * 65 + ty + 32] = acc[1][1];
        __syncthreads();
        if (o0 < DI) {
            for (int i = tid; i < 32 * 64; i += 512) {
                int ol = i >> 6, ll = i & 63;
                xc_t[(size_t)(o0 + ol) * LL + l0 + ll] = ot[ol * 65 + ll];
            }
        } else {
            for (int i = tid; i < 32 * 64; i += 512) {
                int ll = i >> 5, ol = i & 31;
                z_nat[(size_t)(l0 + ll) * DI + (o0 - DI) + ol] = silu_f(ot[ol * 65 + ll]);
            }
        }
    }
    grid.sync();

    // ---------- Stage 2: depthwise conv + transpose (768 = 192 d x 4 bands) ----------
    {
        const int d = gid >> 2;
        const int h0 = (gid & 3) * 14;
        float* in_s = sm;               // 16*56
        float* out_s = sm + 896;        // 14*57
        const float* in = xc_t + (size_t)d * LL;
        for (int i = tid; i < 16 * 14; i += 512) {
            int row = i / 14, q = i % 14;
            int r = row - 1 + h0;
            float4 v = make_float4(0.f, 0.f, 0.f, 0.f);
            if (r >= 0 && r < HH) v = *(const float4*)&in[r * WW + 4 * q];
            *(float4*)&in_s[row * 56 + 4 * q] = v;
        }
        __syncthreads();
        const float b0 = cb[d];
        float w9[9];
#pragma unroll
        for (int i = 0; i < 9; ++i) w9[i] = cw[d * 9 + i];
        for (int i = tid; i < 14 * 56; i += 512) {
            int hh = i / 56, w = i % 56;
            float acc = b0;
#pragma unroll
            for (int di = 0; di < 3; ++di)
#pragma unroll
                for (int dj = 0; dj < 3; ++dj) {
                    int w2 = w + dj - 1;
                    if (w2 < 0 || w2 >= WW) continue;
                    acc = fmaf(in_s[(hh + di) * 56 + w2], w9[di * 3 + dj], acc);
                }
            acc = silu_f(acc);
            xconv[(size_t)d * LL + (h0 + hh) * WW + w] = acc;
            out_s[hh * 57 + w] = acc;
        }
        __syncthreads();
        for (int i = tid; i < 14 * 56; i += 512) {
            int w = i / 14, hh = i % 14;
            xs1[(size_t)d * LL + w * HH + h0 + hh] = out_s[hh * 57 + w];
        }
    }
    grid.sync();

    // ---------- Stage 3: x_dbl + delta (784 tiles of 16 l; blocks<16 loop twice) ----------
    for (int t = gid; t < 784; t += 768) {
        const int k = t & 3, lt = t >> 2;
        const int l0 = lt * 16;
        const float* in = (k & 1) ? xs1 : xconv;
        const float* wk = xpw + (size_t)k * RN * DI;
        float* xt = sm;                 // DI*16 = 3072
        float* wk_s = sm + 3072;        // 32*196 = 6272
        float* dtS = sm + 9344;         // RR*17
        for (int i = tid; i < DI * 4; i += 512) {
            int d = i >> 2, q = i & 3;
            *(float4*)&xt[(d << 4) + 4 * q] = *(const float4*)&in[(size_t)d * LL + l0 + 4 * q];
        }
        for (int i = tid; i < 32 * 48; i += 512) {
            int col = i / 48, q = i % 48;
            *(float4*)&wk_s[col * 196 + 4 * q] = *(const float4*)&wk[RR * DI + col * DI + 4 * q];
        }
        __syncthreads();
        if (tid < RR * 16) {
            int r = tid >> 4, lx = tid & 15;
            const float* wr = wk + r * DI;
            float acc = 0.f;
#pragma unroll 8
            for (int d = 0; d < DI; ++d) acc = fmaf(xt[(d << 4) + lx], wr[d], acc);
            dtS[r * 17 + lx] = acc;
        }
        {
            const int sx = tid & 15, cg2 = tid >> 4;   // cg2 0..31
            float a = 0.f;
            for (int d = 0; d < DI; d += 4) {
                float x0 = xt[(d + 0) * 16 + sx];
                float x1 = xt[(d + 1) * 16 + sx];
                float x2 = xt[(d + 2) * 16 + sx];
                float x3 = xt[(d + 3) * 16 + sx];
                float4 wv = *(const float4*)&wk_s[cg2 * 196 + d];
                a = fmaf(x0, wv.x, a);
                a = fmaf(x1, wv.y, a);
                a = fmaf(x2, wv.z, a);
                a = fmaf(x3, wv.w, a);
            }
            int s = l0 + sx;
            if (cg2 < NS) Bn[((size_t)k * LL + s) * NS + cg2] = a;
            else          Cn[((size_t)k * LL + s) * NS + (cg2 - NS)] = a;
        }
        __syncthreads();
        for (int oi = tid; oi < DI * 16; oi += 512) {
            int d = oi >> 4, sl = oi & 15;
            int kd = k * DI + d;
            const float* wr = dtw + (size_t)kd * RR;
            float acc = dtb[kd];
#pragma unroll
            for (int r = 0; r < RR; ++r) acc = fmaf(dtS[r * 17 + sl], wr[r], acc);
            delta[(size_t)kd * LL + l0 + sl] = softplus_f(acc);
        }
        __syncthreads();
    }
    grid.sync();

    // ---------- Stage 4: selective scan (768 blocks exact, R13 structure) ----------
    {
        float* sP = sm;                 // 1024
        float* sH = sm + 1024;          // 1024
        float* ys = sm + 2048;          // HH*57 = 3192
        const int k = gid / DI, d = gid % DI;
        const int c = tid >> 3, n = tid & 7;
        const int kd = k * DI + d;
        float An0 = -__expf(alog[kd * NS + n]);
        float An1 = -__expf(alog[kd * NS + n + 8]);
        float Dv = Dsp[kd];
        const float* del = delta + (size_t)kd * LL;
        const float* uP  = ((k & 1) ? xs1 : xconv) + (size_t)d * LL;
        const float* Bb  = Bn + (size_t)k * LL * NS;
        const float* Cb  = Cn + (size_t)k * LL * NS;
        float* yo = y4 + (size_t)kd * LL;
        const int t0 = c * CLL;
        const int imF = t0;
        const int imR = LL - 1 - t0;
        if (k == 0) {
            scan_dir<1, false>(del + imF, uP + imF,
                               Bb + (size_t)imF * NS + n, Cb + (size_t)imF * NS + n,
                               An0, An1, Dv, c, n, sP, sH, yo + imF, nullptr, 0);
        } else if (k == 1) {
            scan_dir<1, true>(del + imF, uP + imF,
                              Bb + (size_t)imF * NS + n, Cb + (size_t)imF * NS + n,
                              An0, An1, Dv, c, n, sP, sH, nullptr, ys, imF);
        } else if (k == 2) {
            scan_dir<-1, false>(del + imR, uP + imR,
                                Bb + (size_t)imR * NS + n, Cb + (size_t)imR * NS + n,
                                An0, An1, Dv, c, n, sP, sH, yo + imR, nullptr, 0);
        } else {
            scan_dir<-1, true>(del + imR, uP + imR,
                               Bb + (size_t)imR * NS + n, Cb + (size_t)imR * NS + n,
                               An0, An1, Dv, c, n, sP, sH, nullptr, ys, imR);
        }
        if (k & 1) {
            __syncthreads();
            for (int p = tid; p < LL; p += 512)
                yo[p] = ys[p + p / WW];
        }
    }
    grid.sync();

    // ---------- Stage 5: merge + LN + gate + out-proj (196 tiles of 16 l) ----------
    if (gid < 196) {
        const int l0 = gid * 16;
        float* yv = sm;                 // 16*196 = 3136
        float* ow_s = sm + 3136;        // 48*196 = 9408
        float* mean_s = sm + 12544;     // 16
        float* inv_s = sm + 12560;      // 16
        for (int i = tid; i < DI * 4; i += 512) {
            int d = i >> 2, q = i & 3;
            size_t off = (size_t)d * LL + l0 + 4 * q;
            float4 a = *(const float4*)&y4[off];
            float4 b = *(const float4*)&y4[(size_t)DI * LL + off];
            float4 c2 = *(const float4*)&y4[(size_t)(2 * DI) * LL + off];
            float4 e = *(const float4*)&y4[(size_t)(3 * DI) * LL + off];
            int p = 4 * q;
            yv[(p + 0) * 196 + d] = a.x + b.x + c2.x + e.x;
            yv[(p + 1) * 196 + d] = a.y + b.y + c2.y + e.y;
            yv[(p + 2) * 196 + d] = a.z + b.z + c2.z + e.z;
            yv[(p + 3) * 196 + d] = a.w + b.w + c2.w + e.w;
        }
        __syncthreads();
        if (tid < 256) {
            int p = tid >> 4, e = tid & 15;
            float s1 = 0.f;
#pragma unroll
            for (int m = 0; m < 12; ++m) s1 += yv[p * 196 + e + 16 * m];
            s1 += __shfl_xor(s1, 8, 64);
            s1 += __shfl_xor(s1, 4, 64);
            s1 += __shfl_xor(s1, 2, 64);
            s1 += __shfl_xor(s1, 1, 64);
            float mean = s1 * (1.f / DI);
            float s2 = 0.f;
#pragma unroll
            for (int m = 0; m < 12; ++m) {
                float dv = yv[p * 196 + e + 16 * m] - mean;
                s2 = fmaf(dv, dv, s2);
            }
            s2 += __shfl_xor(s2, 8, 64);
            s2 += __shfl_xor(s2, 4, 64);
            s2 += __shfl_xor(s2, 2, 64);
            s2 += __shfl_xor(s2, 1, 64);
            if (e == 0) {
                mean_s[p] = mean;
                inv_s[p] = rsqrtf(s2 * (1.f / DI) + 1e-5f);
            }
        }
        __syncthreads();
        for (int i = tid; i < 16 * 48; i += 512) {
            int p = i / 48, q = i % 48;
            float4 z4 = *(const float4*)&z_nat[(size_t)(l0 + p) * DI + 4 * q];
            float4 w4 = *(const float4*)&lnw[4 * q];
            float4 b4 = *(const float4*)&lnb[4 * q];
            float4 yy = *(const float4*)&yv[p * 196 + 4 * q];
            float m = mean_s[p], iv = inv_s[p];
            yy.x = ((yy.x - m) * iv * w4.x + b4.x) * z4.x;
            yy.y = ((yy.y - m) * iv * w4.y + b4.y) * z4.y;
            yy.z = ((yy.z - m) * iv * w4.z + b4.z) * z4.z;
            yy.w = ((yy.w - m) * iv * w4.w + b4.w) * z4.w;
            *(float4*)&yv[p * 196 + 4 * q] = yy;
        }
        const int ty = tid >> 5, tx = tid & 31;     // ty: l (0..15), tx: o-lane
#pragma unroll
        for (int pass = 0; pass < 2; ++pass) {
            __syncthreads();
            for (int i = tid; i < 48 * 48; i += 512) {
                int o = i / 48, q = i % 48;
                *(float4*)&ow_s[o * 196 + 4 * q] =
                    *(const float4*)&ow[(size_t)(pass * 48 + o) * DI + 4 * q];
            }
            __syncthreads();
#pragma unroll
            for (int jj = 0; jj < 2; ++jj) {
                int o = tx + 32 * jj;
                if (o < 48) {
                    float a = 0.f;
                    for (int dd = 0; dd < DI; dd += 4) {
                        float4 a0 = *(const float4*)&yv[ty * 196 + dd];
                        float4 bv = *(const float4*)&ow_s[o * 196 + dd];
                        a += a0.x * bv.x + a0.y * bv.y + a0.z * bv.z + a0.w * bv.w;
                    }
                    out[(size_t)(l0 + ty) * DM + pass * 48 + o] = a;
                }
            }
        }
    }
}

// ===================== Fallback path: R13's five proven kernels ==============
__global__ __launch_bounds__(256) void k_inproj(
        const float* __restrict__ x, const float* __restrict__ w,
        float* __restrict__ xc_t, float* __restrict__ z_nat) {
    __shared__ float xt[32 * 100];
    __shared__ float wt[32 * 100];
    const int l0 = blockIdx.x * 32;
    const int o0 = blockIdx.y * 32;
    const int tid = threadIdx.x;
    for (int i = tid; i < 32 * 24; i += 256) {
        int r = i / 24, q = i % 24;
        *(float4*)&xt[r * 100 + 4 * q] = *(const float4*)&x[(size_t)(l0 + r) * DM + 4 * q];
        *(float4*)&wt[r * 100 + 4 * q] = *(const float4*)&w[(size_t)(o0 + r) * DM + 4 * q];
    }
    __syncthreads();
    const int tx = tid & 15, ty = tid >> 4;
    float acc[2][2] = {};
    for (int c = 0; c < 96; c += 4) {
        float4 av[2], bv[2];
#pragma unroll
        for (int i = 0; i < 2; ++i) av[i] = *(const float4*)&xt[(ty + 16 * i) * 100 + c];
#pragma unroll
        for (int j = 0; j < 2; ++j) bv[j] = *(const float4*)&wt[(tx + 16 * j) * 100 + c];
#pragma unroll
        for (int i = 0; i < 2; ++i)
#pragma unroll
            for (int j = 0; j < 2; ++j) {
                acc[i][j] = fmaf(av[i].x, bv[j].x, acc[i][j]);
                acc[i][j] = fmaf(av[i].y, bv[j].y, acc[i][j]);
                acc[i][j] = fmaf(av[i].z, bv[j].z, acc[i][j]);
                acc[i][j] = fmaf(av[i].w, bv[j].w, acc[i][j]);
            }
    }
    __syncthreads();
    float* ot = xt;
#pragma unroll
    for (int j = 0; j < 2; ++j)
#pragma unroll
        for (int i = 0; i < 2; ++i)
            ot[(tx + 16 * j) * 65 + (ty + 16 * i)] = acc[i][j];
    __syncthreads();
    if (o0 < DI) {
        for (int i = tid; i < 32 * 32; i += 256) {
            int ol = i >> 5, ll = i & 31;
            xc_t[(size_t)(o0 + ol) * LL + l0 + ll] = ot[ol * 65 + ll];
        }
    } else {
        for (int i = tid; i < 32 * 32; i += 256) {
            int ll = i >> 5, ol = i & 31;
            z_nat[(size_t)(l0 + ll) * DI + (o0 - DI) + ol] = silu_f(ot[ol * 65 + ll]);
        }
    }
}

__global__ __launch_bounds__(256) void k_convT(
        const float* __restrict__ xc_t, const float* __restrict__ cw,
        const float* __restrict__ cb, float* __restrict__ xconv, float* __restrict__ xs1) {
    __shared__ float in_s[16 * 56];
    __shared__ float out_s[14 * 57];
    const int d = blockIdx.x;
    const int h0 = blockIdx.y * 14;
    const int tid = threadIdx.x;
    const float* in = xc_t + (size_t)d * LL;
    for (int i = tid; i < 16 * 14; i += 256) {
        int row = i / 14, q = i % 14;
        int r = row - 1 + h0;
        float4 v = make_float4(0.f, 0.f, 0.f, 0.f);
        if (r >= 0 && r < HH) v = *(const float4*)&in[r * WW + 4 * q];
        *(float4*)&in_s[row * 56 + 4 * q] = v;
    }
    __syncthreads();
    const float b0 = cb[d];
    float w9[9];
#pragma unroll
    for (int i = 0; i < 9; ++i) w9[i] = cw[d * 9 + i];
    for (int i = tid; i < 14 * 56; i += 256) {
        int hh = i / 56, w = i % 56;
        float acc = b0;
#pragma unroll
        for (int di = 0; di < 3; ++di)
#pragma unroll
            for (int dj = 0; dj < 3; ++dj) {
                int w2 = w + dj - 1;
                if (w2 < 0 || w2 >= WW) continue;
                acc = fmaf(in_s[(hh + di) * 56 + w2], w9[di * 3 + dj], acc);
            }
        acc = silu_f(acc);
        xconv[(size_t)d * LL + (h0 + hh) * WW + w] = acc;
        out_s[hh * 57 + w] = acc;
    }
    __syncthreads();
    for (int i = tid; i < 14 * 56; i += 256) {
        int w = i / 14, hh = i % 14;
        xs1[(size_t)d * LL + w * HH + h0 + hh] = out_s[hh * 57 + w];
    }
}

__global__ __launch_bounds__(256) void k_xdblD(
        const float* __restrict__ xconv, const float* __restrict__ xs1,
        const float* __restrict__ pw, const float* __restrict__ dtw,
        const float* __restrict__ dtb,
        float* __restrict__ Bn, float* __restrict__ Cn, float* __restrict__ delta) {
    __shared__ float xt[DI * 16];
    __shared__ float wk_s[32 * DI];
    __shared__ float dtS[RR * 17];
    const int k = blockIdx.y;
    const int l0 = blockIdx.x * 16;
    const int tid = threadIdx.x;
    const float* in = (k & 1) ? xs1 : xconv;
    const float* wk = pw + (size_t)k * RN * DI;
    for (int i = tid; i < DI * 4; i += 256) {
        int d = i >> 2, q = i & 3;
        *(float4*)&xt[(d << 4) + 4 * q] = *(const float4*)&in[(size_t)d * LL + l0 + 4 * q];
    }
    {
        const float4* src = (const float4*)(wk + RR * DI);
        float4* dst = (float4*)wk_s;
        for (int i = tid; i < (32 * DI) / 4; i += 256) dst[i] = src[i];
    }
    __syncthreads();
    if (tid < RR * 16) {
        int r = tid >> 4, lx = tid & 15;
        const float* wr = wk + r * DI;
        float acc = 0.f;
#pragma unroll 8
        for (int d = 0; d < DI; ++d) acc = fmaf(xt[(d << 4) + lx], wr[d], acc);
        dtS[r * 17 + lx] = acc;
    }
    {
        const int sx = tid & 15, cg = tid >> 4;
        float acc2[2] = {};
        for (int d = 0; d < DI; d += 4) {
            float x0 = xt[(d + 0) * 16 + sx];
            float x1 = xt[(d + 1) * 16 + sx];
            float x2 = xt[(d + 2) * 16 + sx];
            float x3 = xt[(d + 3) * 16 + sx];
#pragma unroll
            for (int j = 0; j < 2; ++j) {
                float4 wv = *(const float4*)&wk_s[(cg + 16 * j) * DI + d];
                acc2[j] = fmaf(x0, wv.x, acc2[j]);
                acc2[j] = fmaf(x1, wv.y, acc2[j]);
                acc2[j] = fmaf(x2, wv.z, acc2[j]);
                acc2[j] = fmaf(x3, wv.w, acc2[j]);
            }
        }
        int s = l0 + sx;
        Bn[((size_t)k * LL + s) * NS + cg] = acc2[0];
        Cn[((size_t)k * LL + s) * NS + cg] = acc2[1];
    }
    __syncthreads();
    for (int oi = tid; oi < DI * 16; oi += 256) {
        int d = oi >> 4, sl = oi & 15;
        int kd = k * DI + d;
        const float* wr = dtw + (size_t)kd * RR;
        float acc = dtb[kd];
#pragma unroll
        for (int r = 0; r < RR; ++r) acc = fmaf(dtS[r * 17 + sl], wr[r], acc);
        delta[(size_t)kd * LL + l0 + sl] = softplus_f(acc);
    }
}

__global__ __launch_bounds__(512) void k_scan(
        const float* __restrict__ delta, const float* __restrict__ Bn,
        const float* __restrict__ Cn,
        const float* __restrict__ xconv, const float* __restrict__ xs1,
        const float* __restrict__ A_logs, const float* __restrict__ Ds,
        float* __restrict__ y4) {
    __shared__ float sP[NCH * NS];
    __shared__ float sH[NCH * NS];
    __shared__ float ys[HH * 57];
    int b = blockIdx.x;
    int k = b / DI, d = b % DI;
    int tid = threadIdx.x;
    int c = tid >> 3, n = tid & 7;
    int kd = k * DI + d;
    float An0 = -__expf(A_logs[kd * NS + n]);
    float An1 = -__expf(A_logs[kd * NS + n + 8]);
    float Dv = Ds[kd];
    const float* del = delta + (size_t)kd * LL;
    const float* uP  = ((k & 1) ? xs1 : xconv) + (size_t)d * LL;
    const float* Bb  = Bn + (size_t)k * LL * NS;
    const float* Cb  = Cn + (size_t)k * LL * NS;
    float* yo = y4 + (size_t)kd * LL;
    const int t0 = c * CLL;
    const int imF = t0;
    const int imR = LL - 1 - t0;
    if (k == 0) {
        scan_dir<1, false>(del + imF, uP + imF,
                           Bb + (size_t)imF * NS + n, Cb + (size_t)imF * NS + n,
                           An0, An1, Dv, c, n, sP, sH, yo + imF, nullptr, 0);
    } else if (k == 1) {
        scan_dir<1, true>(del + imF, uP + imF,
                          Bb + (size_t)imF * NS + n, Cb + (size_t)imF * NS + n,
                          An0, An1, Dv, c, n, sP, sH, nullptr, ys, imF);
    } else if (k == 2) {
        scan_dir<-1, false>(del + imR, uP + imR,
                            Bb + (size_t)imR * NS + n, Cb + (size_t)imR * NS + n,
                            An0, An1, Dv, c, n, sP, sH, yo + imR, nullptr, 0);
    } else {
        scan_dir<-1, true>(del + imR, uP + imR,
                           Bb + (size_t)imR * NS + n, Cb + (size_t)imR * NS + n,
                           An0, An1, Dv, c, n, sP, sH, nullptr, ys, imR);
    }
    if (k & 1) {
        __syncthreads();
        for (int p = tid; p < LL; p += 512)
            yo[p] = ys[p + p / WW];
    }
}

__global__ __launch_bounds__(256) void k_lnout(
        const float* __restrict__ y4, const float* __restrict__ z_nat,
        const float* __restrict__ lnw, const float* __restrict__ lnb,
        const float* __restrict__ ow, float* __restrict__ out) {
    __shared__ float yv[16 * 196];
    __shared__ float ow_s[48 * 196];
    __shared__ float mean_s[16], inv_s[16];
    const int l0 = blockIdx.x * 16;
    const int tid = threadIdx.x;
    for (int i = tid; i < DI * 4; i += 256) {
        int d = i >> 2, q = i & 3;
        size_t off = (size_t)d * LL + l0 + 4 * q;
        float4 a = *(const float4*)&y4[off];
        float4 b = *(const float4*)&y4[(size_t)DI * LL + off];
        float4 c2 = *(const float4*)&y4[(size_t)(2 * DI) * LL + off];
        float4 e = *(const float4*)&y4[(size_t)(3 * DI) * LL + off];
        int p = 4 * q;
        yv[(p + 0) * 196 + d] = a.x + b.x + c2.x + e.x;
        yv[(p + 1) * 196 + d] = a.y + b.y + c2.y + e.y;
        yv[(p + 2) * 196 + d] = a.z + b.z + c2.z + e.z;
        yv[(p + 3) * 196 + d] = a.w + b.w + c2.w + e.w;
    }
    __syncthreads();
    {
        int p = tid >> 4, e = tid & 15;
        float s1 = 0.f;
#pragma unroll
        for (int m = 0; m < 12; ++m) s1 += yv[p * 196 + e + 16 * m];
        s1 += __shfl_xor(s1, 8, 64);
        s1 += __shfl_xor(s1, 4, 64);
        s1 += __shfl_xor(s1, 2, 64);
        s1 += __shfl_xor(s1, 1, 64);
        float mean = s1 * (1.f / DI);
        float s2 = 0.f;
#pragma unroll
        for (int m = 0; m < 12; ++m) {
            float dv = yv[p * 196 + e + 16 * m] - mean;
            s2 = fmaf(dv, dv, s2);
        }
        s2 += __shfl_xor(s2, 8, 64);
        s2 += __shfl_xor(s2, 4, 64);
        s2 += __shfl_xor(s2, 2, 64);
        s2 += __shfl_xor(s2, 1, 64);
        if (e == 0) {
            mean_s[p] = mean;
            inv_s[p] = rsqrtf(s2 * (1.f / DI) + 1e-5f);
        }
    }
    __syncthreads();
    for (int i = tid; i < 16 * 48; i += 256) {
        int p = i / 48, q = i % 48;
        float4 z4 = *(const float4*)&z_nat[(size_t)(l0 + p) * DI + 4 * q];
        float4 w4 = *(const float4*)&lnw[4 * q];
        float4 b4 = *(const float4*)&lnb[4 * q];
        float4 yy = *(const float4*)&yv[p * 196 + 4 * q];
        float m = mean_s[p], iv = inv_s[p];
        yy.x = ((yy.x - m) * iv * w4.x + b4.x) * z4.x;
        yy.y = ((yy.y - m) * iv * w4.y + b4.y) * z4.y;
        yy.z = ((yy.z - m) * iv * w4.z + b4.z) * z4.z;
        yy.w = ((yy.w - m) * iv * w4.w + b4.w) * z4.w;
        *(float4*)&yv[p * 196 + 4 * q] = yy;
    }
    const int ty = tid >> 4, tx = tid & 15;
#pragma unroll
    for (int pass = 0; pass < 2; ++pass) {
        __syncthreads();
        for (int i = tid; i < 48 * 48; i += 256) {
            int o = i / 48, q = i % 48;
            *(float4*)&ow_s[o * 196 + 4 * q] =
                *(const float4*)&ow[(size_t)(pass * 48 + o) * DI + 4 * q];
        }
        __syncthreads();
        float acc[3] = {};
        for (int dd = 0; dd < DI; dd += 4) {
            float4 a0 = *(const float4*)&yv[ty * 196 + dd];
#pragma unroll
            for (int j = 0; j < 3; ++j) {
                float4 bv = *(const float4*)&ow_s[(tx + 16 * j) * 196 + dd];
                acc[j] += a0.x * bv.x + a0.y * bv.y + a0.z * bv.z + a0.w * bv.w;
            }
        }
#pragma unroll
        for (int j = 0; j < 3; ++j)
            out[(size_t)(l0 + ty) * DM + pass * 48 + tx + 16 * j] = acc[j];
    }
}

extern "C" void kernel_launch(void* const* d_in, const int* in_sizes, int n_in,
                              void* d_out, int out_size, void* d_ws, size_t ws_size,
                              hipStream_t stream) {
    const float* x    = (const float*)d_in[0];
    const float* ipw  = (const float*)d_in[1];
    const float* cw   = (const float*)d_in[2];
    const float* cb   = (const float*)d_in[3];
    const float* xpw  = (const float*)d_in[4];
    const float* dtw  = (const float*)d_in[5];
    const float* dtb  = (const float*)d_in[6];
    const float* alog = (const float*)d_in[7];
    const float* Dsp  = (const float*)d_in[8];
    const float* lnw  = (const float*)d_in[9];
    const float* lnb  = (const float*)d_in[10];
    const float* ow   = (const float*)d_in[11];
    float* out = (float*)d_out;

    float* ws     = (float*)d_ws;
    float* xc_t   = ws;                             // DI*LL
    float* z_nat  = xc_t + DI * LL;                 // LL*DI
    float* xconv  = z_nat + DI * LL;                // DI*LL
    float* xs1    = xconv + DI * LL;                // DI*LL
    float* Bn     = xs1 + DI * LL;                  // KK*LL*NS
    float* Cn     = Bn + (size_t)KK * LL * NS;      // KK*LL*NS
    float* delta  = Cn + (size_t)KK * LL * NS;      // KK*DI*LL
    float* y4     = delta + (size_t)KK * DI * LL;   // KK*DI*LL (natural p)

    void* kargs[] = {
        (void*)&x, (void*)&ipw, (void*)&cw, (void*)&cb, (void*)&xpw,
        (void*)&dtw, (void*)&dtb, (void*)&alog, (void*)&Dsp, (void*)&lnw,
        (void*)&lnb, (void*)&ow, (void*)&out,
        (void*)&xc_t, (void*)&z_nat, (void*)&xconv, (void*)&xs1,
        (void*)&Bn, (void*)&Cn, (void*)&delta, (void*)&y4
    };
    hipError_t err = hipLaunchCooperativeKernel((void*)k_fused, dim3(768), dim3(512),
                                                kargs, 0, stream);
    if (err != hipSuccess) {
        // Deterministic fallback: proven R13 5-kernel sequence.
        k_inproj <<<dim3(LL / 32, 12), 256, 0, stream>>>(x, ipw, xc_t, z_nat);
        k_convT  <<<dim3(DI, 4), 256, 0, stream>>>(xc_t, cw, cb, xconv, xs1);
        k_xdblD  <<<dim3(LL / 16, KK), 256, 0, stream>>>(xconv, xs1, xpw, dtw, dtb, Bn, Cn, delta);
        k_scan   <<<KK * DI, 512, 0, stream>>>(delta, Bn, Cn, xconv, xs1, alog, Dsp, y4);
        k_lnout  <<<LL / 16, 256, 0, stream>>>(y4, z_nat, lnw, lnb, ow, out);
    }
}

// Round 15
// 195.384 us; speedup vs baseline: 2.8137x; 2.8137x over previous
//
#include <hip/hip_runtime.h>
#include <hip/hip_bf16.h>
#include <math.h>

// SS2D (VMamba) forward, MI355X. Constants from the reference.
#define DM 96
#define DI 192
#define NS 16
#define KK 4
#define RR 6
#define HH 56
#define WW 56
#define LL (HH*WW)       // 3136
#define RN (RR + 2*NS)   // 38
#define NCH 64
#define CLL (LL/NCH)     // 49

__device__ __forceinline__ float silu_f(float x) { return x / (1.f + __expf(-x)); }
__device__ __forceinline__ float softplus_f(float x) {
    return (x > 20.f) ? x : log1pf(__expf(x));
}

// K1: fused in-proj + depthwise conv + spatial transpose, one CHANNEL per block.
// Grid 384: b<192 -> xc channel d (dot -> conv -> silu -> xconv[d][l], xs1[d][s]);
// b>=192 -> z channel (dot -> silu -> z_t[zc][l]).
// x (1.2 MB) is L2-resident; each block streams it with zero inner-loop syncs.
__global__ __launch_bounds__(256) void k_fuse1(
        const float* __restrict__ x, const float* __restrict__ ipw,
        const float* __restrict__ cw, const float* __restrict__ cb,
        float* __restrict__ xconv, float* __restrict__ xs1,
        float* __restrict__ z_t) {
    __shared__ float row_s[LL];                     // 12.5 KB: channel pre-act map
    __shared__ float out_s[HH * 57];                // 12.8 KB: conv-out transpose tile
    const int b = blockIdx.x;
    const int tid = threadIdx.x;
    const bool zpath = (b >= DI);
    const int orow = b;                             // ipw row (0..383)
    const int d = zpath ? (b - DI) : b;

    // per-thread w slice: part covers 24 of 96 input channels
    const int ol = tid >> 2, part = tid & 3;
    float4 wreg[6];
    {
        const float* wr = ipw + (size_t)orow * DM + part * 24;
#pragma unroll
        for (int j = 0; j < 6; ++j) wreg[j] = *(const float4*)&wr[4 * j];
    }
    // dot loop: 49 tiles of 64 l, no syncs (independent iterations)
    for (int t = 0; t < 49; ++t) {
        int l = t * 64 + ol;
        const float* xr = x + (size_t)l * DM + part * 24;
        float acc = 0.f;
#pragma unroll
        for (int j = 0; j < 6; ++j) {
            float4 xv = *(const float4*)&xr[4 * j];
            acc += xv.x * wreg[j].x + xv.y * wreg[j].y
                 + xv.z * wreg[j].z + xv.w * wreg[j].w;
        }
        acc += __shfl_xor(acc, 1, 64);
        acc += __shfl_xor(acc, 2, 64);
        if (part == 0) row_s[l] = acc;
    }
    __syncthreads();

    if (zpath) {
        // z = silu(row), coalesced write to z_t[zc][l]
        float* zo = z_t + (size_t)d * LL;
        for (int i = tid; i < LL; i += 256)
            zo[i] = silu_f(row_s[i]);
        return;
    }
    // conv 3x3 SAME + bias + silu from the in-LDS map
    const float b0 = cb[d];
    float w9[9];
#pragma unroll
    for (int i = 0; i < 9; ++i) w9[i] = cw[d * 9 + i];
    for (int i = tid; i < LL; i += 256) {
        int h = i / WW, w = i % WW;
        float acc = b0;
#pragma unroll
        for (int di = 0; di < 3; ++di) {
            int hh = h + di - 1;
            if (hh < 0 || hh >= HH) continue;
#pragma unroll
            for (int dj = 0; dj < 3; ++dj) {
                int w2 = w + dj - 1;
                if (w2 < 0 || w2 >= WW) continue;
                acc = fmaf(row_s[hh * WW + w2], w9[di * 3 + dj], acc);
            }
        }
        acc = silu_f(acc);
        xconv[(size_t)d * LL + i] = acc;
        out_s[h * 57 + w] = acc;
    }
    __syncthreads();
    float* xo = xs1 + (size_t)d * LL;
    for (int s = tid; s < LL; s += 256)
        xo[s] = out_s[(s % HH) * 57 + s / HH];
}

// K2: x_dbl + delta fused, l-tile 16. Both operands LDS-staged. Grid (196, 4).
__global__ __launch_bounds__(256) void k_xdblD(
        const float* __restrict__ xconv, const float* __restrict__ xs1,
        const float* __restrict__ pw, const float* __restrict__ dtw,
        const float* __restrict__ dtb,
        float* __restrict__ Bn, float* __restrict__ Cn, float* __restrict__ delta) {
    __shared__ float xt[DI * 16];
    __shared__ float wk_s[32 * DI];
    __shared__ float dtS[RR * 17];
    const int k = blockIdx.y;
    const int l0 = blockIdx.x * 16;
    const int tid = threadIdx.x;
    const float* in = (k & 1) ? xs1 : xconv;
    const float* wk = pw + (size_t)k * RN * DI;
    for (int i = tid; i < DI * 4; i += 256) {
        int d = i >> 2, q = i & 3;
        *(float4*)&xt[(d << 4) + 4 * q] = *(const float4*)&in[(size_t)d * LL + l0 + 4 * q];
    }
    {
        const float4* src = (const float4*)(wk + RR * DI);
        float4* dst = (float4*)wk_s;
        for (int i = tid; i < (32 * DI) / 4; i += 256) dst[i] = src[i];
    }
    __syncthreads();
    if (tid < RR * 16) {
        int r = tid >> 4, lx = tid & 15;
        const float* wr = wk + r * DI;
        float acc = 0.f;
#pragma unroll 8
        for (int d = 0; d < DI; ++d) acc = fmaf(xt[(d << 4) + lx], wr[d], acc);
        dtS[r * 17 + lx] = acc;
    }
    {
        const int sx = tid & 15, cg = tid >> 4;
        float acc2[2] = {};
        for (int d = 0; d < DI; d += 4) {
            float x0 = xt[(d + 0) * 16 + sx];
            float x1 = xt[(d + 1) * 16 + sx];
            float x2 = xt[(d + 2) * 16 + sx];
            float x3 = xt[(d + 3) * 16 + sx];
#pragma unroll
            for (int j = 0; j < 2; ++j) {
                float4 wv = *(const float4*)&wk_s[(cg + 16 * j) * DI + d];
                acc2[j] = fmaf(x0, wv.x, acc2[j]);
                acc2[j] = fmaf(x1, wv.y, acc2[j]);
                acc2[j] = fmaf(x2, wv.z, acc2[j]);
                acc2[j] = fmaf(x3, wv.w, acc2[j]);
            }
        }
        int s = l0 + sx;
        Bn[((size_t)k * LL + s) * NS + cg] = acc2[0];
        Cn[((size_t)k * LL + s) * NS + cg] = acc2[1];
    }
    __syncthreads();
    for (int oi = tid; oi < DI * 16; oi += 256) {
        int d = oi >> 4, sl = oi & 15;
        int kd = k * DI + d;
        const float* wr = dtw + (size_t)kd * RR;
        float acc = dtb[kd];
#pragma unroll
        for (int r = 0; r < RR; ++r) acc = fmaf(dtS[r * 17 + sl], wr[r], acc);
        delta[(size_t)kd * LL + l0 + sl] = softplus_f(acc);
    }
}

// ---- scan body (R13-proven): 8 lanes/chunk, 2 states/lane ----
template<int STP, bool TRANS>
__device__ __forceinline__ void scan_dir(
        const float* __restrict__ pd, const float* __restrict__ pu,
        const float* __restrict__ pB, const float* __restrict__ pC,
        float An0, float An1, float Dv, int c, int n,
        float* __restrict__ sP, float* __restrict__ sH,
        float* __restrict__ yo0, float* __restrict__ ysm, int im0) {
    float sd = 0.f, h0 = 0.f, h1 = 0.f;
#pragma unroll 7
    for (int tl = 0; tl < CLL; ++tl) {
        float dl = pd[STP * tl];
        float u  = pu[STP * tl];
        float B0 = pB[STP * NS * tl];
        float B1 = pB[STP * NS * tl + 8];
        float dA0 = __expf(dl * An0);
        float dA1 = __expf(dl * An1);
        float du = dl * u;
        h0 = fmaf(dA0, h0, du * B0);
        h1 = fmaf(dA1, h1, du * B1);
        sd += dl;
    }
    sP[c * NS + n]     = __expf(sd * An0);
    sP[c * NS + n + 8] = __expf(sd * An1);
    sH[c * NS + n]     = h0;
    sH[c * NS + n + 8] = h1;
    __syncthreads();
    float hin0 = 0.f, hin1 = 0.f;
    for (int cc = 0; cc < c; ++cc) {
        hin0 = fmaf(sP[cc * NS + n],     hin0, sH[cc * NS + n]);
        hin1 = fmaf(sP[cc * NS + n + 8], hin1, sH[cc * NS + n + 8]);
    }
    float h20 = hin0, h21 = hin1;
    float yreg[7];
#pragma unroll 7
    for (int tl = 0; tl < CLL; ++tl) {
        float dl = pd[STP * tl];
        float u  = pu[STP * tl];
        float B0 = pB[STP * NS * tl];
        float B1 = pB[STP * NS * tl + 8];
        float C0 = pC[STP * NS * tl];
        float C1 = pC[STP * NS * tl + 8];
        float dA0 = __expf(dl * An0);
        float dA1 = __expf(dl * An1);
        float du = dl * u;
        h20 = fmaf(dA0, h20, du * B0);
        h21 = fmaf(dA1, h21, du * B1);
        float acc = h20 * C0 + h21 * C1;
        acc += __shfl_xor(acc, 4, 64);
        acc += __shfl_xor(acc, 2, 64);
        acc += __shfl_xor(acc, 1, 64);
        acc = fmaf(Dv, u, acc);
        if ((tl & 7) == n) yreg[tl >> 3] = acc;
    }
    if (!TRANS) {
#pragma unroll
        for (int j = 0; j < 6; ++j)
            yo0[STP * (j * 8 + n)] = yreg[j];
        if (n == 0)
            yo0[STP * 48] = yreg[6];
    } else {
#pragma unroll
        for (int j = 0; j < 6; ++j) {
            int im = im0 + STP * (j * 8 + n);
            int w = im / HH, hh = im - w * HH;
            ysm[hh * 57 + w] = yreg[j];
        }
        if (n == 0) {
            int im = im0 + STP * 48;
            int w = im / HH, hh = im - w * HH;
            ysm[hh * 57 + w] = yreg[6];
        }
    }
}

// K3: chunked selective scan; 512 threads. y4[kd][p] in NATURAL space.
__global__ __launch_bounds__(512) void k_scan(
        const float* __restrict__ delta, const float* __restrict__ Bn,
        const float* __restrict__ Cn,
        const float* __restrict__ xconv, const float* __restrict__ xs1,
        const float* __restrict__ A_logs, const float* __restrict__ Ds,
        float* __restrict__ y4) {
    __shared__ float sP[NCH * NS];
    __shared__ float sH[NCH * NS];
    __shared__ float ys[HH * 57];
    int b = blockIdx.x;
    int k = b / DI, d = b % DI;
    int tid = threadIdx.x;
    int c = tid >> 3, n = tid & 7;
    int kd = k * DI + d;
    float An0 = -__expf(A_logs[kd * NS + n]);
    float An1 = -__expf(A_logs[kd * NS + n + 8]);
    float Dv = Ds[kd];
    const float* del = delta + (size_t)kd * LL;
    const float* uP  = ((k & 1) ? xs1 : xconv) + (size_t)d * LL;
    const float* Bb  = Bn + (size_t)k * LL * NS;
    const float* Cb  = Cn + (size_t)k * LL * NS;
    float* yo = y4 + (size_t)kd * LL;
    const int t0 = c * CLL;
    const int imF = t0;
    const int imR = LL - 1 - t0;
    if (k == 0) {
        scan_dir<1, false>(del + imF, uP + imF,
                           Bb + (size_t)imF * NS + n, Cb + (size_t)imF * NS + n,
                           An0, An1, Dv, c, n, sP, sH, yo + imF, nullptr, 0);
    } else if (k == 1) {
        scan_dir<1, true>(del + imF, uP + imF,
                          Bb + (size_t)imF * NS + n, Cb + (size_t)imF * NS + n,
                          An0, An1, Dv, c, n, sP, sH, nullptr, ys, imF);
    } else if (k == 2) {
        scan_dir<-1, false>(del + imR, uP + imR,
                            Bb + (size_t)imR * NS + n, Cb + (size_t)imR * NS + n,
                            An0, An1, Dv, c, n, sP, sH, yo + imR, nullptr, 0);
    } else {
        scan_dir<-1, true>(del + imR, uP + imR,
                           Bb + (size_t)imR * NS + n, Cb + (size_t)imR * NS + n,
                           An0, An1, Dv, c, n, sP, sH, nullptr, ys, imR);
    }
    if (k & 1) {
        __syncthreads();
        for (int p = tid; p < LL; p += 512)
            yo[p] = ys[p + p / WW];
    }
}

// K4: merge + LN + gate(z_t) + out-proj (two sequential 48-o passes). Grid 196.
__global__ __launch_bounds__(256) void k_lnout(
        const float* __restrict__ y4, const float* __restrict__ z_t,
        const float* __restrict__ lnw, const float* __restrict__ lnb,
        const float* __restrict__ ow, float* __restrict__ out) {
    __shared__ float yv[16 * 196];
    __shared__ float ow_s[48 * 196];
    __shared__ float mean_s[16], inv_s[16];
    const int l0 = blockIdx.x * 16;
    const int tid = threadIdx.x;
    for (int i = tid; i < DI * 4; i += 256) {
        int d = i >> 2, q = i & 3;
        size_t off = (size_t)d * LL + l0 + 4 * q;
        float4 a = *(const float4*)&y4[off];
        float4 b = *(const float4*)&y4[(size_t)DI * LL + off];
        float4 c2 = *(const float4*)&y4[(size_t)(2 * DI) * LL + off];
        float4 e = *(const float4*)&y4[(size_t)(3 * DI) * LL + off];
        int p = 4 * q;
        yv[(p + 0) * 196 + d] = a.x + b.x + c2.x + e.x;
        yv[(p + 1) * 196 + d] = a.y + b.y + c2.y + e.y;
        yv[(p + 2) * 196 + d] = a.z + b.z + c2.z + e.z;
        yv[(p + 3) * 196 + d] = a.w + b.w + c2.w + e.w;
    }
    __syncthreads();
    {
        int p = tid >> 4, e = tid & 15;
        float s1 = 0.f;
#pragma unroll
        for (int m = 0; m < 12; ++m) s1 += yv[p * 196 + e + 16 * m];
        s1 += __shfl_xor(s1, 8, 64);
        s1 += __shfl_xor(s1, 4, 64);
        s1 += __shfl_xor(s1, 2, 64);
        s1 += __shfl_xor(s1, 1, 64);
        float mean = s1 * (1.f / DI);
        float s2 = 0.f;
#pragma unroll
        for (int m = 0; m < 12; ++m) {
            float dv = yv[p * 196 + e + 16 * m] - mean;
            s2 = fmaf(dv, dv, s2);
        }
        s2 += __shfl_xor(s2, 8, 64);
        s2 += __shfl_xor(s2, 4, 64);
        s2 += __shfl_xor(s2, 2, 64);
        s2 += __shfl_xor(s2, 1, 64);
        if (e == 0) {
            mean_s[p] = mean;
            inv_s[p] = rsqrtf(s2 * (1.f / DI) + 1e-5f);
        }
    }
    __syncthreads();
    // normalize + gate: z_t[d][l] rows, float4 over p
    for (int i = tid; i < DI * 4; i += 256) {
        int d = i >> 2, q = i & 3;
        float4 zz = *(const float4*)&z_t[(size_t)d * LL + l0 + 4 * q];
        float wv = lnw[d], bv = lnb[d];
        const float zf[4] = {zz.x, zz.y, zz.z, zz.w};
#pragma unroll
        for (int j = 0; j < 4; ++j) {
            int p = 4 * q + j;
            float yn = (yv[p * 196 + d] - mean_s[p]) * inv_s[p] * wv + bv;
            yv[p * 196 + d] = yn * zf[j];
        }
    }
    const int ty = tid >> 4, tx = tid & 15;
#pragma unroll
    for (int pass = 0; pass < 2; ++pass) {
        __syncthreads();
        for (int i = tid; i < 48 * 48; i += 256) {
            int o = i / 48, q = i % 48;
            *(float4*)&ow_s[o * 196 + 4 * q] =
                *(const float4*)&ow[(size_t)(pass * 48 + o) * DI + 4 * q];
        }
        __syncthreads();
        float acc[3] = {};
        for (int dd = 0; dd < DI; dd += 4) {
            float4 a0 = *(const float4*)&yv[ty * 196 + dd];
#pragma unroll
            for (int j = 0; j < 3; ++j) {
                float4 bv = *(const float4*)&ow_s[(tx + 16 * j) * 196 + dd];
                acc[j] += a0.x * bv.x + a0.y * bv.y + a0.z * bv.z + a0.w * bv.w;
            }
        }
#pragma unroll
        for (int j = 0; j < 3; ++j)
            out[(size_t)(l0 + ty) * DM + pass * 48 + tx + 16 * j] = acc[j];
    }
}

extern "C" void kernel_launch(void* const* d_in, const int* in_sizes, int n_in,
                              void* d_out, int out_size, void* d_ws, size_t ws_size,
                              hipStream_t stream) {
    const float* x    = (const float*)d_in[0];
    const float* ipw  = (const float*)d_in[1];
    const float* cw   = (const float*)d_in[2];
    const float* cb   = (const float*)d_in[3];
    const float* xpw  = (const float*)d_in[4];
    const float* dtw  = (const float*)d_in[5];
    const float* dtb  = (const float*)d_in[6];
    const float* alog = (const float*)d_in[7];
    const float* Dsp  = (const float*)d_in[8];
    const float* lnw  = (const float*)d_in[9];
    const float* lnb  = (const float*)d_in[10];
    const float* ow   = (const float*)d_in[11];
    float* out = (float*)d_out;

    float* ws     = (float*)d_ws;
    float* z_t    = ws;                             // DI*LL
    float* xconv  = z_t + DI * LL;                  // DI*LL
    float* xs1    = xconv + DI * LL;                // DI*LL
    float* Bn     = xs1 + DI * LL;                  // KK*LL*NS
    float* Cn     = Bn + (size_t)KK * LL * NS;      // KK*LL*NS
    float* delta  = Cn + (size_t)KK * LL * NS;      // KK*DI*LL
    float* y4     = delta + (size_t)KK * DI * LL;   // KK*DI*LL (natural p)

    k_fuse1 <<<2 * DI, 256, 0, stream>>>(x, ipw, cw, cb, xconv, xs1, z_t);
    k_xdblD <<<dim3(LL / 16, KK), 256, 0, stream>>>(xconv, xs1, xpw, dtw, dtb, Bn, Cn, delta);
    k_scan  <<<KK * DI, 512, 0, stream>>>(delta, Bn, Cn, xconv, xs1, alog, Dsp, y4);
    k_lnout <<<LL / 16, 256, 0, stream>>>(y4, z_t, lnw, lnb, ow, out);
}

// Round 16
// 176.803 us; speedup vs baseline: 3.1094x; 1.1051x over previous
//
#include <hip/hip_runtime.h>
#include <hip/hip_bf16.h>
#include <math.h>

// SS2D (VMamba) forward, MI355X. Constants from the reference.
// R16 = revert to R13 (measured best: 176.5 us). R14 (coop grid.sync ~90us each)
// and R15 (per-channel fusion: 38x L2 re-read of x) both regressed.
#define DM 96
#define DI 192
#define NS 16            // state dim N
#define KK 4             // directions
#define RR 6             // dt rank
#define HH 56
#define WW 56
#define LL (HH*WW)       // 3136
#define RN (RR + 2*NS)   // 38 rows of x_dbl
#define NCH 64           // scan chunks per sequence
#define CLL (LL/NCH)     // 49 steps per chunk

__device__ __forceinline__ float silu_f(float x) { return x / (1.f + __expf(-x)); }
__device__ __forceinline__ float softplus_f(float x) {
    return (x > 20.f) ? x : log1pf(__expf(x));
}

// K1: tiled GEMM xz[o][l]; 32l x 32o tiles, grid (98, 12).
__global__ __launch_bounds__(256) void k_inproj(
        const float* __restrict__ x, const float* __restrict__ w,
        float* __restrict__ xc_t, float* __restrict__ z_nat) {
    __shared__ float xt[32 * 100];
    __shared__ float wt[32 * 100];
    const int l0 = blockIdx.x * 32;
    const int o0 = blockIdx.y * 32;
    const int tid = threadIdx.x;
    for (int i = tid; i < 32 * 24; i += 256) {
        int r = i / 24, q = i % 24;
        *(float4*)&xt[r * 100 + 4 * q] = *(const float4*)&x[(size_t)(l0 + r) * DM + 4 * q];
        *(float4*)&wt[r * 100 + 4 * q] = *(const float4*)&w[(size_t)(o0 + r) * DM + 4 * q];
    }
    __syncthreads();
    const int tx = tid & 15, ty = tid >> 4;        // tx: o, ty: l
    float acc[2][2] = {};
    for (int c = 0; c < 96; c += 4) {
        float4 av[2], bv[2];
#pragma unroll
        for (int i = 0; i < 2; ++i) av[i] = *(const float4*)&xt[(ty + 16 * i) * 100 + c];
#pragma unroll
        for (int j = 0; j < 2; ++j) bv[j] = *(const float4*)&wt[(tx + 16 * j) * 100 + c];
#pragma unroll
        for (int i = 0; i < 2; ++i)
#pragma unroll
            for (int j = 0; j < 2; ++j) {
                acc[i][j] = fmaf(av[i].x, bv[j].x, acc[i][j]);
                acc[i][j] = fmaf(av[i].y, bv[j].y, acc[i][j]);
                acc[i][j] = fmaf(av[i].z, bv[j].z, acc[i][j]);
                acc[i][j] = fmaf(av[i].w, bv[j].w, acc[i][j]);
            }
    }
    __syncthreads();
    float* ot = xt;                                // reuse as [o][l] 32x65
#pragma unroll
    for (int j = 0; j < 2; ++j)
#pragma unroll
        for (int i = 0; i < 2; ++i)
            ot[(tx + 16 * j) * 65 + (ty + 16 * i)] = acc[i][j];
    __syncthreads();
    if (o0 < DI) {
        for (int i = tid; i < 32 * 32; i += 256) {
            int ol = i >> 5, ll = i & 31;
            xc_t[(size_t)(o0 + ol) * LL + l0 + ll] = ot[ol * 65 + ll];
        }
    } else {
        for (int i = tid; i < 32 * 32; i += 256) {
            int ll = i >> 5, ol = i & 31;
            z_nat[(size_t)(l0 + ll) * DI + (o0 - DI) + ol] = silu_f(ot[ol * 65 + ll]);
        }
    }
}

// K2: depthwise 3x3 conv SAME + bias + silu + spatial transpose, band-split.
__global__ __launch_bounds__(256) void k_convT(
        const float* __restrict__ xc_t, const float* __restrict__ cw,
        const float* __restrict__ cb, float* __restrict__ xconv, float* __restrict__ xs1) {
    __shared__ float in_s[16 * 56];
    __shared__ float out_s[14 * 57];
    const int d = blockIdx.x;
    const int h0 = blockIdx.y * 14;
    const int tid = threadIdx.x;
    const float* in = xc_t + (size_t)d * LL;
    for (int i = tid; i < 16 * 14; i += 256) {
        int row = i / 14, q = i % 14;
        int r = row - 1 + h0;
        float4 v = make_float4(0.f, 0.f, 0.f, 0.f);
        if (r >= 0 && r < HH) v = *(const float4*)&in[r * WW + 4 * q];
        *(float4*)&in_s[row * 56 + 4 * q] = v;
    }
    __syncthreads();
    const float b0 = cb[d];
    float w9[9];
#pragma unroll
    for (int i = 0; i < 9; ++i) w9[i] = cw[d * 9 + i];
    for (int i = tid; i < 14 * 56; i += 256) {
        int hh = i / 56, w = i % 56;
        float acc = b0;
#pragma unroll
        for (int di = 0; di < 3; ++di)
#pragma unroll
            for (int dj = 0; dj < 3; ++dj) {
                int w2 = w + dj - 1;
                if (w2 < 0 || w2 >= WW) continue;
                acc = fmaf(in_s[(hh + di) * 56 + w2], w9[di * 3 + dj], acc);
            }
        acc = silu_f(acc);
        xconv[(size_t)d * LL + (h0 + hh) * WW + w] = acc;
        out_s[hh * 57 + w] = acc;
    }
    __syncthreads();
    for (int i = tid; i < 14 * 56; i += 256) {
        int w = i / 14, hh = i % 14;
        xs1[(size_t)d * LL + w * HH + h0 + hh] = out_s[hh * 57 + w];
    }
}

// K3: x_dbl + delta fused, l-tile 16. Both operands LDS-staged. Grid (196, 4).
__global__ __launch_bounds__(256) void k_xdblD(
        const float* __restrict__ xconv, const float* __restrict__ xs1,
        const float* __restrict__ pw, const float* __restrict__ dtw,
        const float* __restrict__ dtb,
        float* __restrict__ Bn, float* __restrict__ Cn, float* __restrict__ delta) {
    __shared__ float xt[DI * 16];                  // [d][sx], 12 KB
    __shared__ float wk_s[32 * DI];                // [col][d], 24.6 KB
    __shared__ float dtS[RR * 17];
    const int k = blockIdx.y;
    const int l0 = blockIdx.x * 16;
    const int tid = threadIdx.x;
    const float* in = (k & 1) ? xs1 : xconv;
    const float* wk = pw + (size_t)k * RN * DI;
    for (int i = tid; i < DI * 4; i += 256) {
        int d = i >> 2, q = i & 3;
        *(float4*)&xt[(d << 4) + 4 * q] = *(const float4*)&in[(size_t)d * LL + l0 + 4 * q];
    }
    {
        const float4* src = (const float4*)(wk + RR * DI);
        float4* dst = (float4*)wk_s;
        for (int i = tid; i < (32 * DI) / 4; i += 256) dst[i] = src[i];
    }
    __syncthreads();
    if (tid < RR * 16) {
        int r = tid >> 4, lx = tid & 15;
        const float* wr = wk + r * DI;
        float acc = 0.f;
#pragma unroll 8
        for (int d = 0; d < DI; ++d) acc = fmaf(xt[(d << 4) + lx], wr[d], acc);
        dtS[r * 17 + lx] = acc;
    }
    {
        const int sx = tid & 15, cg = tid >> 4;    // cg in [0,16)
        float acc2[2] = {};
        for (int d = 0; d < DI; d += 4) {
            float x0 = xt[(d + 0) * 16 + sx];
            float x1 = xt[(d + 1) * 16 + sx];
            float x2 = xt[(d + 2) * 16 + sx];
            float x3 = xt[(d + 3) * 16 + sx];
#pragma unroll
            for (int j = 0; j < 2; ++j) {
                float4 wv = *(const float4*)&wk_s[(cg + 16 * j) * DI + d];
                acc2[j] = fmaf(x0, wv.x, acc2[j]);
                acc2[j] = fmaf(x1, wv.y, acc2[j]);
                acc2[j] = fmaf(x2, wv.z, acc2[j]);
                acc2[j] = fmaf(x3, wv.w, acc2[j]);
            }
        }
        int s = l0 + sx;
        Bn[((size_t)k * LL + s) * NS + cg] = acc2[0];   // cols 0..15
        Cn[((size_t)k * LL + s) * NS + cg] = acc2[1];   // cols 16..31
    }
    __syncthreads();
    for (int oi = tid; oi < DI * 16; oi += 256) {
        int d = oi >> 4, sl = oi & 15;
        int kd = k * DI + d;
        const float* wr = dtw + (size_t)kd * RR;
        float acc = dtb[kd];
#pragma unroll
        for (int r = 0; r < RR; ++r) acc = fmaf(dtS[r * 17 + sl], wr[r], acc);
        delta[(size_t)kd * LL + l0 + sl] = softplus_f(acc);
    }
}

// ---- templated scan body: 8 lanes per chunk, 2 states per lane (n and n+8).
template<int STP, bool TRANS>
__device__ __forceinline__ void scan_dir(
        const float* __restrict__ pd, const float* __restrict__ pu,
        const float* __restrict__ pB, const float* __restrict__ pC,
        float An0, float An1, float Dv, int c, int n,
        float* __restrict__ sP, float* __restrict__ sH,
        float* __restrict__ yo0,   // !TRANS: direction-adjusted global base
        float* __restrict__ ysm,   // TRANS: LDS tile [HH][57]
        int im0) {
    float sd = 0.f, h0 = 0.f, h1 = 0.f;
#pragma unroll 7
    for (int tl = 0; tl < CLL; ++tl) {
        float dl = pd[STP * tl];
        float u  = pu[STP * tl];
        float B0 = pB[STP * NS * tl];
        float B1 = pB[STP * NS * tl + 8];
        float dA0 = __expf(dl * An0);
        float dA1 = __expf(dl * An1);
        float du = dl * u;
        h0 = fmaf(dA0, h0, du * B0);
        h1 = fmaf(dA1, h1, du * B1);
        sd += dl;
    }
    sP[c * NS + n]     = __expf(sd * An0);
    sP[c * NS + n + 8] = __expf(sd * An1);
    sH[c * NS + n]     = h0;
    sH[c * NS + n + 8] = h1;
    __syncthreads();
    float hin0 = 0.f, hin1 = 0.f;
    for (int cc = 0; cc < c; ++cc) {
        hin0 = fmaf(sP[cc * NS + n],     hin0, sH[cc * NS + n]);
        hin1 = fmaf(sP[cc * NS + n + 8], hin1, sH[cc * NS + n + 8]);
    }
    float h20 = hin0, h21 = hin1;
    float yreg[7];
#pragma unroll 7
    for (int tl = 0; tl < CLL; ++tl) {
        float dl = pd[STP * tl];
        float u  = pu[STP * tl];
        float B0 = pB[STP * NS * tl];
        float B1 = pB[STP * NS * tl + 8];
        float C0 = pC[STP * NS * tl];
        float C1 = pC[STP * NS * tl + 8];
        float dA0 = __expf(dl * An0);
        float dA1 = __expf(dl * An1);
        float du = dl * u;
        h20 = fmaf(dA0, h20, du * B0);
        h21 = fmaf(dA1, h21, du * B1);
        float acc = h20 * C0 + h21 * C1;
        acc += __shfl_xor(acc, 4, 64);
        acc += __shfl_xor(acc, 2, 64);
        acc += __shfl_xor(acc, 1, 64);
        acc = fmaf(Dv, u, acc);
        if ((tl & 7) == n) yreg[tl >> 3] = acc;
    }
    if (!TRANS) {
#pragma unroll
        for (int j = 0; j < 6; ++j)
            yo0[STP * (j * 8 + n)] = yreg[j];
        if (n == 0)
            yo0[STP * 48] = yreg[6];
    } else {
#pragma unroll
        for (int j = 0; j < 6; ++j) {
            int im = im0 + STP * (j * 8 + n);
            int w = im / HH, hh = im - w * HH;
            ysm[hh * 57 + w] = yreg[j];
        }
        if (n == 0) {
            int im = im0 + STP * 48;
            int w = im / HH, hh = im - w * HH;
            ysm[hh * 57 + w] = yreg[6];
        }
    }
}

// K4: chunked selective scan; 512 threads. y4[kd][p] in NATURAL space.
__global__ __launch_bounds__(512) void k_scan(
        const float* __restrict__ delta, const float* __restrict__ Bn,
        const float* __restrict__ Cn,
        const float* __restrict__ xconv, const float* __restrict__ xs1,
        const float* __restrict__ A_logs, const float* __restrict__ Ds,
        float* __restrict__ y4) {
    __shared__ float sP[NCH * NS];
    __shared__ float sH[NCH * NS];
    __shared__ float ys[HH * 57];                  // k-odd transpose tile
    int b = blockIdx.x;
    int k = b / DI, d = b % DI;
    int tid = threadIdx.x;
    int c = tid >> 3, n = tid & 7;
    int kd = k * DI + d;
    float An0 = -__expf(A_logs[kd * NS + n]);
    float An1 = -__expf(A_logs[kd * NS + n + 8]);
    float Dv = Ds[kd];
    const float* del = delta + (size_t)kd * LL;
    const float* uP  = ((k & 1) ? xs1 : xconv) + (size_t)d * LL;
    const float* Bb  = Bn + (size_t)k * LL * NS;
    const float* Cb  = Cn + (size_t)k * LL * NS;
    float* yo = y4 + (size_t)kd * LL;
    const int t0 = c * CLL;
    const int imF = t0;
    const int imR = LL - 1 - t0;
    if (k == 0) {
        scan_dir<1, false>(del + imF, uP + imF,
                           Bb + (size_t)imF * NS + n, Cb + (size_t)imF * NS + n,
                           An0, An1, Dv, c, n, sP, sH, yo + imF, nullptr, 0);
    } else if (k == 1) {
        scan_dir<1, true>(del + imF, uP + imF,
                          Bb + (size_t)imF * NS + n, Cb + (size_t)imF * NS + n,
                          An0, An1, Dv, c, n, sP, sH, nullptr, ys, imF);
    } else if (k == 2) {
        scan_dir<-1, false>(del + imR, uP + imR,
                            Bb + (size_t)imR * NS + n, Cb + (size_t)imR * NS + n,
                            An0, An1, Dv, c, n, sP, sH, yo + imR, nullptr, 0);
    } else {
        scan_dir<-1, true>(del + imR, uP + imR,
                           Bb + (size_t)imR * NS + n, Cb + (size_t)imR * NS + n,
                           An0, An1, Dv, c, n, sP, sH, nullptr, ys, imR);
    }
    if (k & 1) {                         // block-uniform branch
        __syncthreads();
        for (int p = tid; p < LL; p += 512)
            yo[p] = ys[p + p / WW];      // [h][w] tile, stride 57
    }
}

// K5: merge 4 natural rows + LayerNorm + gate(z) ONCE, then out-proj in two
// sequential 48-o passes (ow_s restaged). 16 l per block; grid 196.
__global__ __launch_bounds__(256) void k_lnout(
        const float* __restrict__ y4, const float* __restrict__ z_nat,
        const float* __restrict__ lnw, const float* __restrict__ lnb,
        const float* __restrict__ ow, float* __restrict__ out) {
    __shared__ float yv[16 * 196];
    __shared__ float ow_s[48 * 196];
    __shared__ float mean_s[16], inv_s[16];
    const int l0 = blockIdx.x * 16;
    const int tid = threadIdx.x;
    for (int i = tid; i < DI * 4; i += 256) {
        int d = i >> 2, q = i & 3;
        size_t off = (size_t)d * LL + l0 + 4 * q;
        float4 a = *(const float4*)&y4[off];
        float4 b = *(const float4*)&y4[(size_t)DI * LL + off];
        float4 c2 = *(const float4*)&y4[(size_t)(2 * DI) * LL + off];
        float4 e = *(const float4*)&y4[(size_t)(3 * DI) * LL + off];
        int p = 4 * q;
        yv[(p + 0) * 196 + d] = a.x + b.x + c2.x + e.x;
        yv[(p + 1) * 196 + d] = a.y + b.y + c2.y + e.y;
        yv[(p + 2) * 196 + d] = a.z + b.z + c2.z + e.z;
        yv[(p + 3) * 196 + d] = a.w + b.w + c2.w + e.w;
    }
    __syncthreads();
    {
        int p = tid >> 4, e = tid & 15;
        float s1 = 0.f;
#pragma unroll
        for (int m = 0; m < 12; ++m) s1 += yv[p * 196 + e + 16 * m];
        s1 += __shfl_xor(s1, 8, 64);
        s1 += __shfl_xor(s1, 4, 64);
        s1 += __shfl_xor(s1, 2, 64);
        s1 += __shfl_xor(s1, 1, 64);
        float mean = s1 * (1.f / DI);
        float s2 = 0.f;
#pragma unroll
        for (int m = 0; m < 12; ++m) {
            float dv = yv[p * 196 + e + 16 * m] - mean;
            s2 = fmaf(dv, dv, s2);
        }
        s2 += __shfl_xor(s2, 8, 64);
        s2 += __shfl_xor(s2, 4, 64);
        s2 += __shfl_xor(s2, 2, 64);
        s2 += __shfl_xor(s2, 1, 64);
        if (e == 0) {
            mean_s[p] = mean;
            inv_s[p] = rsqrtf(s2 * (1.f / DI) + 1e-5f);
        }
    }
    __syncthreads();
    for (int i = tid; i < 16 * 48; i += 256) {
        int p = i / 48, q = i % 48;
        float4 z4 = *(const float4*)&z_nat[(size_t)(l0 + p) * DI + 4 * q];
        float4 w4 = *(const float4*)&lnw[4 * q];
        float4 b4 = *(const float4*)&lnb[4 * q];
        float4 yy = *(const float4*)&yv[p * 196 + 4 * q];
        float m = mean_s[p], iv = inv_s[p];
        yy.x = ((yy.x - m) * iv * w4.x + b4.x) * z4.x;
        yy.y = ((yy.y - m) * iv * w4.y + b4.y) * z4.y;
        yy.z = ((yy.z - m) * iv * w4.z + b4.z) * z4.z;
        yy.w = ((yy.w - m) * iv * w4.w + b4.w) * z4.w;
        *(float4*)&yv[p * 196 + 4 * q] = yy;
    }
    const int ty = tid >> 4, tx = tid & 15;        // ty: l, tx: o
#pragma unroll
    for (int pass = 0; pass < 2; ++pass) {
        __syncthreads();
        for (int i = tid; i < 48 * 48; i += 256) {
            int o = i / 48, q = i % 48;
            *(float4*)&ow_s[o * 196 + 4 * q] =
                *(const float4*)&ow[(size_t)(pass * 48 + o) * DI + 4 * q];
        }
        __syncthreads();
        float acc[3] = {};
        for (int dd = 0; dd < DI; dd += 4) {
            float4 a0 = *(const float4*)&yv[ty * 196 + dd];
#pragma unroll
            for (int j = 0; j < 3; ++j) {
                float4 bv = *(const float4*)&ow_s[(tx + 16 * j) * 196 + dd];
                acc[j] += a0.x * bv.x + a0.y * bv.y + a0.z * bv.z + a0.w * bv.w;
            }
        }
#pragma unroll
        for (int j = 0; j < 3; ++j)
            out[(size_t)(l0 + ty) * DM + pass * 48 + tx + 16 * j] = acc[j];
    }
}

extern "C" void kernel_launch(void* const* d_in, const int* in_sizes, int n_in,
                              void* d_out, int out_size, void* d_ws, size_t ws_size,
                              hipStream_t stream) {
    const float* x    = (const float*)d_in[0];
    const float* ipw  = (const float*)d_in[1];
    const float* cw   = (const float*)d_in[2];
    const float* cb   = (const float*)d_in[3];
    const float* xpw  = (const float*)d_in[4];
    const float* dtw  = (const float*)d_in[5];
    const float* dtb  = (const float*)d_in[6];
    const float* alog = (const float*)d_in[7];
    const float* Dsp  = (const float*)d_in[8];
    const float* lnw  = (const float*)d_in[9];
    const float* lnb  = (const float*)d_in[10];
    const float* ow   = (const float*)d_in[11];
    float* out = (float*)d_out;

    float* ws     = (float*)d_ws;
    float* xc_t   = ws;                             // DI*LL (dead after convT)
    float* z_nat  = xc_t + DI * LL;                 // LL*DI
    float* xconv  = z_nat + DI * LL;                // DI*LL
    float* xs1    = xconv + DI * LL;                // DI*LL
    float* Bn     = xs1 + DI * LL;                  // KK*LL*NS
    float* Cn     = Bn + (size_t)KK * LL * NS;      // KK*LL*NS
    float* delta  = Cn + (size_t)KK * LL * NS;      // KK*DI*LL
    float* y4     = delta + (size_t)KK * DI * LL;   // KK*DI*LL (natural p)

    k_inproj <<<dim3(LL / 32, 12), 256, 0, stream>>>(x, ipw, xc_t, z_nat);
    k_convT  <<<dim3(DI, 4), 256, 0, stream>>>(xc_t, cw, cb, xconv, xs1);
    k_xdblD  <<<dim3(LL / 16, KK), 256, 0, stream>>>(xconv, xs1, xpw, dtw, dtb, Bn, Cn, delta);
    k_scan   <<<KK * DI, 512, 0, stream>>>(delta, Bn, Cn, xconv, xs1, alog, Dsp, y4);
    k_lnout  <<<LL / 16, 256, 0, stream>>>(y4, z_nat, lnw, lnb, ow, out);
}